// Round 6
// baseline (263.043 us; speedup 1.0000x reference)
//
#include <hip/hip_runtime.h>
#include <stdint.h>

#define N_TOK 2048
#define C_DIM 1024
#define H_DIM 2048
#define NE 8
#define NSLOT 3

#define BM 128
#define BN 64
#define BK 64
#define PGRID 1024   // persistent: 256 CU x 4 resident (25KB LDS, <=128 VGPR)

// ws layout (bytes); every section multiple of 256
#define WS_COUNTS   0
#define WS_PLAN     256
#define WS_CW       (WS_PLAN + 1024)
#define WS_LISTS    (WS_CW + N_TOK*NE*4)
#define WS_XB       (WS_LISTS + NE*N_TOK*4)
#define WS_HBUF     (WS_XB + (size_t)N_TOK*C_DIM*2)
#define WS_OUTSLOT  (WS_HBUF + (size_t)N_TOK*NSLOT*H_DIM*2)
#define WS_WT13     (WS_OUTSLOT + (size_t)N_TOK*NSLOT*C_DIM*4)
#define WS_WT2T     (WS_WT13 + (size_t)NE*2*H_DIM*C_DIM*2)

typedef short bf16x8 __attribute__((ext_vector_type(8)));
typedef float f32x4 __attribute__((ext_vector_type(4)));

union FragU { bf16x8 v; uint2 u2[2]; };

__device__ __forceinline__ unsigned short f2b(float f) {
    union { float f; uint32_t u; } v; v.f = f;
    return (unsigned short)((v.u + 0x7fffu + ((v.u >> 16) & 1u)) >> 16); // RNE
}

// async global->LDS, 16B per lane; lds dest is wave-uniform base + lane*16
__device__ __forceinline__ void gload16(const unsigned short* g, unsigned short* l) {
    __builtin_amdgcn_global_load_lds(
        (const __attribute__((address_space(1))) unsigned int*)g,
        (__attribute__((address_space(3))) unsigned int*)l, 16, 0, 0);
}

__global__ void zero_kernel(int* counts) {
    if (threadIdx.x < NE) counts[threadIdx.x] = 0;
}

// ---- conflict-free 64x64 transpose+cast: src [E][K][N] fp32 -> dst [E][Nr][K] bf16
// dst row R = ((n>>4)<<Rshift)+(n&15)+Roff.
// Write phase: lane=(kp,nn), pack (k,k+1)->u32, ds_write_b32 into chunk-XOR
// swizzled [n][k] tile: banks = 4*((k0>>3)^(n&7)) + kp -> 32 distinct, 2 lanes
// each (free). Read phase: ds_read_b128 (saturated, conflict-free), 64B-contig
// global writes.
__device__ __forceinline__ void tcast_tile(
        const float* __restrict__ src, unsigned short* __restrict__ dst,
        int K, int N, int Rshift, int Roff, int e, int Nr, int k0t, int n0t,
        unsigned short* lds, int t) {
    const int lane = t & 63, wv = t >> 6;
    const int kp = lane >> 4, nn = lane & 15;
    const int n = wv * 16 + nn;                  // 0..63
    const float* s = src + ((size_t)e * K + k0t) * N + n0t + n;
    char* lb = (char*)lds;
#pragma unroll
    for (int k0 = 0; k0 < 64; k0 += 8) {
        int k = k0 + 2 * kp;
        float lo = s[(size_t)k * N];
        float hi = s[(size_t)(k + 1) * N];
        uint32_t p = (uint32_t)f2b(lo) | ((uint32_t)f2b(hi) << 16);
        *(uint32_t*)(lb + n * 128 + (((k0 >> 3) ^ (n & 7)) << 4) + (kp << 2)) = p;
    }
    __syncthreads();
    const int r = t >> 2, cp = t & 3;
    const int gn = n0t + r;
    const int R = ((gn >> 4) << Rshift) + (gn & 15) + Roff;
    unsigned short* drow = dst + ((size_t)e * Nr + R) * K + k0t;
#pragma unroll
    for (int i = 0; i < 2; i++) {
        int cc = cp + 4 * i;
        uint4 v = *(const uint4*)(lb + r * 128 + ((cc ^ (r & 7)) << 4));
        *(uint4*)(drow + cc * 8) = v;
    }
}

// ---------------- fused gate + w1/w3 tcast ----------------
// blocks 0..511: gating (4 tokens/block, 1 wave/token)
// blocks 512..8703: w1/w3 transpose tiles (op = bb>>12, e = (bb>>9)&7)
__global__ __launch_bounds__(256) void gate_tcast_kernel(
        const float* __restrict__ x, const float* __restrict__ gw,
        const float* __restrict__ gb, const float* __restrict__ w1,
        const float* __restrict__ w3, float* __restrict__ cw,
        unsigned short* __restrict__ xb, int* __restrict__ counts,
        int* __restrict__ lists, unsigned short* __restrict__ wt13) {
    __shared__ __align__(16) unsigned short tl[64 * 64];
    if (blockIdx.x >= 512) {
        int bb = blockIdx.x - 512;
        int op = bb >> 12, e = (bb >> 9) & 7, tb = bb & 511;
        tcast_tile(op ? w3 : w1, wt13, C_DIM, H_DIM, 5, op ? 16 : 0,
                   e, 2 * H_DIM, (tb & 15) * 64, (tb >> 4) * 64, tl, threadIdx.x);
        return;
    }
    int n = (blockIdx.x * 256 + threadIdx.x) >> 6;
    int lane = threadIdx.x & 63;
    float acc[NE];
#pragma unroll
    for (int e = 0; e < NE; e++) acc[e] = 0.f;
    for (int c = lane; c < C_DIM; c += 64) {
        float xv = x[n * C_DIM + c];
        xb[n * C_DIM + c] = f2b(xv);
        const float* g = gw + c * NE;
#pragma unroll
        for (int e = 0; e < NE; e++) acc[e] += xv * g[e];
    }
#pragma unroll
    for (int e = 0; e < NE; e++) {
#pragma unroll
        for (int off = 32; off >= 1; off >>= 1) acc[e] += __shfl_xor(acc[e], off, 64);
        acc[e] += gb[e];
    }
    float m = acc[0];
#pragma unroll
    for (int e = 1; e < NE; e++) m = fmaxf(m, acc[e]);
    float s = 0.f, sc[NE];
#pragma unroll
    for (int e = 0; e < NE; e++) { sc[e] = __expf(acc[e] - m); s += sc[e]; }
    float inv = 1.f / s;
#pragma unroll
    for (int e = 0; e < NE; e++) sc[e] *= inv;
    // top-2 of routed experts 1..7; ties -> lower index (matches lax.top_k)
    int i1 = 1; float v1 = sc[1];
#pragma unroll
    for (int e = 2; e < NE; e++) if (sc[e] > v1) { v1 = sc[e]; i1 = e; }
    int i2 = 0; float v2 = -1.f;
#pragma unroll
    for (int e = 1; e < NE; e++) if (e != i1 && sc[e] > v2) { v2 = sc[e]; i2 = e; }
    if (lane < NE) {
        float v = 0.f;
        if (lane == 0) v = sc[0];
        else if (lane == i1) v = v1;
        else if (lane == i2) v = v2;
        cw[n * NE + lane] = v;
    }
    if (lane == 0) {  // entry = token*4 + slot
        int p0 = atomicAdd(&counts[0], 1);  lists[p0] = n * 4 + 0;
        int p1 = atomicAdd(&counts[i1], 1); lists[i1 * N_TOK + p1] = n * 4 + 1;
        int p2 = atomicAdd(&counts[i2], 1); lists[i2 * N_TOK + p2] = n * 4 + 2;
    }
}

// ---------------- plan: compacted (expert, m-block) work list ----------------
__global__ void plan_kernel(const int* __restrict__ counts, int* __restrict__ plan) {
    if (threadIdx.x == 0) {
        int p = 0;
        for (int e = 0; e < NE; e++) {
            int nb = (counts[e] + BM - 1) / BM;
            for (int m = 0; m < nb; m++) plan[1 + p++] = (e << 8) | m;
        }
        plan[0] = p;
    }
}

// STAGE: 4 A-chunks + 2 B-chunks per lane (async 16B global->LDS)
#define STAGE(koff) do {                                                  \
    _Pragma("unroll")                                                     \
    for (int i_ = 0; i_ < 4; i_++)                                        \
        gload16(asrc[i_] + (koff), As + (i_ * 256 + t) * 8);              \
    _Pragma("unroll")                                                     \
    for (int i_ = 0; i_ < 2; i_++)                                        \
        gload16(bsrc[i_] + (koff), Bs + (i_ * 256 + t) * 8);              \
} while (0)

// COMPUTE: 12 ds_read_b128 + 16 MFMA on one 128x64x64 tile (wave tile 64x32)
#define COMPUTE() do {                                                    \
    __builtin_amdgcn_s_setprio(1);                                        \
    _Pragma("unroll")                                                     \
    for (int j_ = 0; j_ < 2; j_++) {                                      \
        FragU af[4], bf[2];                                               \
        _Pragma("unroll")                                                 \
        for (int mt = 0; mt < 4; mt++) {                                  \
            int row = wr * 64 + mt * 16 + ln15;                           \
            int slot = (j_ * 4 + lg) ^ swz;                               \
            af[mt].v = *(const bf16x8*)(As + row * BK + slot * 8);        \
        }                                                                 \
        _Pragma("unroll")                                                 \
        for (int nt = 0; nt < 2; nt++) {                                  \
            int row = wc * 32 + nt * 16 + ln15;                           \
            int slot = (j_ * 4 + lg) ^ swz;                               \
            bf[nt].v = *(const bf16x8*)(Bs + row * BK + slot * 8);        \
        }                                                                 \
        _Pragma("unroll")                                                 \
        for (int mt = 0; mt < 4; mt++)                                    \
            _Pragma("unroll")                                             \
            for (int nt = 0; nt < 2; nt++)                                \
                acc[mt][nt] = __builtin_amdgcn_mfma_f32_16x16x32_bf16(    \
                    af[mt].v, bf[nt].v, acc[mt][nt], 0, 0, 0);            \
    }                                                                     \
    __builtin_amdgcn_s_setprio(0);                                        \
} while (0)

// single-buffer K-loop: latency hiding via 4 blocks/CU TLP (m114 mechanism)
#define KLOOP(NK) do {                                                    \
    for (int kt = 0; kt < (NK); kt++) {                                   \
        STAGE(kt * BK);                                                   \
        asm volatile("s_waitcnt vmcnt(0)" ::: "memory");                  \
        __builtin_amdgcn_s_barrier();                                     \
        COMPUTE();                                                        \
        __builtin_amdgcn_s_barrier();                                     \
    }                                                                     \
} while (0)

// -------- persistent expert up (blocks < PGRID) + w2 tcast (blocks >= PGRID) --------
__global__ __launch_bounds__(256, 4) void expert_up_kernel(
        const unsigned short* __restrict__ xb, const unsigned short* __restrict__ wt13,
        const float* __restrict__ b1, const float* __restrict__ b3,
        const int* __restrict__ counts, const int* __restrict__ lists,
        const int* __restrict__ plan, unsigned short* __restrict__ hbuf,
        const float* __restrict__ w2, unsigned short* __restrict__ wt2t) {
    const int t = threadIdx.x;

    __shared__ __align__(16) unsigned short As[BM * BK];  // 16 KB (tcast reuses 8KB)
    __shared__ __align__(16) unsigned short Bs[BN * BK];  // 8 KB
    __shared__ int rowtok[BM];

    if (blockIdx.x >= PGRID) {   // w2 -> wt2t tiles, overlapped with GEMM tail
        int bb = blockIdx.x - PGRID;
        int e = bb >> 9, tb = bb & 511;
        tcast_tile(w2, wt2t, H_DIM, C_DIM, 4, 0,
                   e, C_DIM, (tb >> 4) * 64, (tb & 15) * 64, As, t);
        return;
    }

    const int lane = t & 63, w = t >> 6;
    const int ln15 = lane & 15, lg = lane >> 4;
    const int wr = w >> 1, wc = w & 1;
    const int swz = ln15 & 7;

    const int ntile = plan[0] << 6;   // nmb * 64 n-blocks (N = 2H = 4096)
    for (int tile = blockIdx.x; tile < ntile; tile += PGRID) {
        const int mi = tile >> 6, nb = tile & 63;
        const int ent = plan[1 + mi];
        const int e = ent >> 8, m0 = (ent & 255) * BM;
        const int cnt = counts[e];
        const int n0 = nb * BN;

        if (t < BM) {
            int r = m0 + t;  // tail rows duplicate last valid token (benign)
            rowtok[t] = lists[e * N_TOK + (r < cnt ? r : cnt - 1)];
        }
        __syncthreads();

        const unsigned short* wtb = wt13 + (size_t)e * (2 * H_DIM) * C_DIM;
        const unsigned short* asrc[4];
        const unsigned short* bsrc[2];
#pragma unroll
        for (int i = 0; i < 4; i++) {   // A chunk c: row=c>>3, holds kc=(c&7)^(row&7)
            int c = i * 256 + t;
            int row = c >> 3, kc = (c & 7) ^ (row & 7);
            asrc[i] = xb + (size_t)(rowtok[row] >> 2) * C_DIM + kc * 8;
        }
#pragma unroll
        for (int i = 0; i < 2; i++) {
            int c = i * 256 + t;
            int row = c >> 3, kc = (c & 7) ^ (row & 7);
            bsrc[i] = wtb + (size_t)(n0 + row) * C_DIM + kc * 8;
        }

        f32x4 acc[4][2];
#pragma unroll
        for (int a = 0; a < 4; a++)
#pragma unroll
            for (int b = 0; b < 2; b++) acc[a][b] = (f32x4){0.f, 0.f, 0.f, 0.f};

        KLOOP(C_DIM / BK);

        // epilogue: wave's 32 B-rows: nt=0 -> w1 (a), nt=1 -> w3 (g)
        {
            int h = ((n0 + wc * 32) >> 5) * 16 + ln15;
            float bb1 = b1[e * H_DIM + h], bb3 = b3[e * H_DIM + h];
#pragma unroll
            for (int mt = 0; mt < 4; mt++) {
#pragma unroll
                for (int jj = 0; jj < 4; jj++) {
                    int mrow = wr * 64 + mt * 16 + lg * 4 + jj;  // C/D row=(lane>>4)*4+reg
                    float av = acc[mt][0][jj] + bb1;
                    float gv = acc[mt][1][jj] + bb3;
                    float hv = av * gv / (1.f + __expf(-gv));    // silu(g)*a
                    int ent2 = rowtok[mrow];
                    hbuf[(size_t)((ent2 >> 2) * NSLOT + (ent2 & 3)) * H_DIM + h] = f2b(hv);
                }
            }
        }
        __syncthreads();   // protect rowtok/LDS before next tile
    }
}

// -------- persistent expert down: [h rows] x [w2^T], K = H --------
__global__ __launch_bounds__(256, 4) void expert_down_kernel(
        const unsigned short* __restrict__ hbuf, const unsigned short* __restrict__ wt2t,
        const float* __restrict__ b2, const float* __restrict__ cw,
        const int* __restrict__ counts, const int* __restrict__ lists,
        const int* __restrict__ plan, float* __restrict__ outslot) {
    const int t = threadIdx.x;
    const int lane = t & 63, w = t >> 6;
    const int ln15 = lane & 15, lg = lane >> 4;
    const int wr = w >> 1, wc = w & 1;
    const int swz = ln15 & 7;

    __shared__ __align__(16) unsigned short As[BM * BK];
    __shared__ __align__(16) unsigned short Bs[BN * BK];
    __shared__ int rowtok[BM];

    const int ntile = plan[0] << 4;   // nmb * 16 c-blocks (N = C = 1024)
    for (int tile = blockIdx.x; tile < ntile; tile += PGRID) {
        const int mi = tile >> 4, nb = tile & 15;
        const int ent = plan[1 + mi];
        const int e = ent >> 8, m0 = (ent & 255) * BM;
        const int cnt = counts[e];
        const int c0 = nb * BN;

        if (t < BM) {
            int r = m0 + t;
            rowtok[t] = lists[e * N_TOK + (r < cnt ? r : cnt - 1)];
        }
        __syncthreads();

        const unsigned short* wtb = wt2t + (size_t)e * C_DIM * H_DIM;
        const unsigned short* asrc[4];
        const unsigned short* bsrc[2];
#pragma unroll
        for (int i = 0; i < 4; i++) {
            int c = i * 256 + t;
            int row = c >> 3, kc = (c & 7) ^ (row & 7);
            int ent2 = rowtok[row];
            asrc[i] = hbuf + (size_t)((ent2 >> 2) * NSLOT + (ent2 & 3)) * H_DIM + kc * 8;
        }
#pragma unroll
        for (int i = 0; i < 2; i++) {
            int c = i * 256 + t;
            int row = c >> 3, kc = (c & 7) ^ (row & 7);
            bsrc[i] = wtb + (size_t)(c0 + row) * H_DIM + kc * 8;
        }

        f32x4 acc[4][2];
#pragma unroll
        for (int a = 0; a < 4; a++)
#pragma unroll
            for (int b = 0; b < 2; b++) acc[a][b] = (f32x4){0.f, 0.f, 0.f, 0.f};

        KLOOP(H_DIM / BK);

#pragma unroll
        for (int nt = 0; nt < 2; nt++) {
            int col = c0 + wc * 32 + nt * 16 + ln15;
            float bb = b2[e * C_DIM + col];
#pragma unroll
            for (int mt = 0; mt < 4; mt++) {
#pragma unroll
                for (int jj = 0; jj < 4; jj++) {
                    int mrow = wr * 64 + mt * 16 + lg * 4 + jj;
                    int ent2 = rowtok[mrow];
                    int tok = ent2 >> 2, slot = ent2 & 3;
                    float cwv = cw[tok * NE + e];
                    outslot[(size_t)(tok * NSLOT + slot) * C_DIM + col] =
                        cwv * (acc[mt][nt][jj] + bb);
                }
            }
        }
        __syncthreads();
    }
}

// -------- fused reduce (blocks 0..2047) + balance loss (block 2048) --------
__global__ __launch_bounds__(256) void reduce_loss_kernel(
        const float* __restrict__ os, const float* __restrict__ cw,
        const int* __restrict__ counts, float* __restrict__ out) {
    if (blockIdx.x < 2048) {
        int i = blockIdx.x * 256 + threadIdx.x;   // over N*C/4
        int n = i >> 8;
        int c = (i & 255) * 4;
        const float4 s0 = *(const float4*)(os + ((size_t)n * NSLOT + 0) * C_DIM + c);
        const float4 s1 = *(const float4*)(os + ((size_t)n * NSLOT + 1) * C_DIM + c);
        const float4 s2 = *(const float4*)(os + ((size_t)n * NSLOT + 2) * C_DIM + c);
        float4 r;
        r.x = s0.x + s1.x + s2.x; r.y = s0.y + s1.y + s2.y;
        r.z = s0.z + s1.z + s2.z; r.w = s0.w + s1.w + s2.w;
        *(float4*)(out + (size_t)n * C_DIM + c) = r;
    } else if (threadIdx.x < 64) {
        int lane = threadIdx.x;
        float ss[NE];
#pragma unroll
        for (int e = 0; e < NE; e++) ss[e] = 0.f;
        for (int n = lane; n < N_TOK; n += 64) {
#pragma unroll
            for (int e = 0; e < NE; e++) ss[e] += cw[n * NE + e];
        }
#pragma unroll
        for (int e = 0; e < NE; e++) {
#pragma unroll
            for (int off = 32; off >= 1; off >>= 1) ss[e] += __shfl_xor(ss[e], off, 64);
        }
        if (lane == 0) {
            float bal = 0.f;
            const float fac = (float)NE / (3.f * (float)N_TOK * (float)N_TOK);
#pragma unroll
            for (int e = 0; e < NE; e++) bal += fac * (float)counts[e] * ss[e];
            out[(size_t)N_TOK * C_DIM] = bal;
        }
    }
}

extern "C" void kernel_launch(void* const* d_in, const int* in_sizes, int n_in,
                              void* d_out, int out_size, void* d_ws, size_t ws_size,
                              hipStream_t stream) {
    const float* x  = (const float*)d_in[0];
    const float* gw = (const float*)d_in[1];
    const float* gb = (const float*)d_in[2];
    const float* w1 = (const float*)d_in[3];
    const float* b1 = (const float*)d_in[4];
    const float* w2 = (const float*)d_in[5];
    const float* b2 = (const float*)d_in[6];
    const float* w3 = (const float*)d_in[7];
    const float* b3 = (const float*)d_in[8];
    float* out = (float*)d_out;
    char* ws = (char*)d_ws;
    int*            counts = (int*)(ws + WS_COUNTS);
    int*            plan   = (int*)(ws + WS_PLAN);
    float*          cw     = (float*)(ws + WS_CW);
    int*            lists  = (int*)(ws + WS_LISTS);
    unsigned short* xb     = (unsigned short*)(ws + WS_XB);
    unsigned short* hbuf   = (unsigned short*)(ws + WS_HBUF);
    float*          oslot  = (float*)(ws + WS_OUTSLOT);
    unsigned short* wt13   = (unsigned short*)(ws + WS_WT13);
    unsigned short* wt2t   = (unsigned short*)(ws + WS_WT2T);

    hipLaunchKernelGGL(zero_kernel, dim3(1), dim3(64), 0, stream, counts);
    hipLaunchKernelGGL(gate_tcast_kernel, dim3(512 + 8192), dim3(256), 0, stream,
                       x, gw, gb, w1, w3, cw, xb, counts, lists, wt13);
    hipLaunchKernelGGL(plan_kernel, dim3(1), dim3(64), 0, stream, counts, plan);
    hipLaunchKernelGGL(expert_up_kernel, dim3(PGRID + 4096), dim3(256), 0, stream,
                       xb, wt13, b1, b3, counts, lists, plan, hbuf, w2, wt2t);
    hipLaunchKernelGGL(expert_down_kernel, dim3(PGRID), dim3(256), 0, stream,
                       hbuf, wt2t, b2, cw, counts, lists, plan, oslot);
    hipLaunchKernelGGL(reduce_loss_kernel, dim3(2049), dim3(256), 0, stream,
                       oslot, cw, counts, out);
}